// Round 1
// baseline (3002.540 us; speedup 1.0000x reference)
//
#include <hip/hip_runtime.h>
#include <math.h>

// Problem constants
#define CC 62
#define TT_TOTAL 2000
#define BB 256
#define VECN 1953          // C*(C+1)/2
#define HID 64
#define NCLS 3
#define NPART 4            // t-parts for covariance partials
#define TCHUNK 500         // TT_TOTAL / NPART
#define TILE_T 100         // t-tile inside a part (5 tiles per part)
#define NTILES 5
#define NPAIR2 992         // sum_i ceil((62-i)/2)

// ---------------------------------------------------------------------------
// K1: conv1d(k=1) in fp32 + fp64 partial Grammian S = sum_t xc xc^T and
//     partial sums m = sum_t xc over a 500-sample t-chunk.
// grid = (B, NPART), block = 256
// ---------------------------------------------------------------------------
__global__ __launch_bounds__(256) void k1_cov(
    const float* __restrict__ x, const float* __restrict__ cw,
    const float* __restrict__ cb, double* __restrict__ S,
    double* __restrict__ M)
{
    const int b    = blockIdx.x;
    const int part = blockIdx.y;
    const int tid  = threadIdx.x;

    __shared__ float sW[CC * CC];          // 15376 B
    __shared__ float sX[CC * TILE_T];      // stride 100 (only t-consecutive access)
    __shared__ float sXC[CC * 101];        // stride 101 (odd-ish for cov j-access)

    for (int idx = tid; idx < CC * CC; idx += 256) sW[idx] = cw[idx];

    // conv thread mapping: tid -> (oq, ts); 4 output rows, strided t
    const int oq = tid >> 4;          // 0..15
    const int ts = tid & 15;          // 0..15
    const int o0 = oq * 4;
    const int nrow = (CC - o0) < 4 ? (CC - o0) : 4;   // 4 or 2
    float bias_r[4];
    for (int l = 0; l < 4; ++l) bias_r[l] = (l < nrow) ? cb[o0 + l] : 0.0f;

    // covariance item setup: items are (i, j0) with j0=i+2*rem, two j's each
    int ii[4], jj[4];
    double acc0[4], acc1[4];
    int nit = 0;
    for (int s = 0; s < 4; ++s) {
        int item = tid + s * 256;
        if (item < NPAIR2) {
            int rem = item, i = 0;
            while (true) { int cnt = (63 - i) >> 1; if (rem < cnt) break; rem -= cnt; ++i; }
            ii[s] = i; jj[s] = i + 2 * rem;
            acc0[s] = 0.0; acc1[s] = 0.0;
            nit = s + 1;
        }
    }
    double macc = 0.0;

    const int t_base = part * TCHUNK;
    for (int tile = 0; tile < NTILES; ++tile) {
        const int t0 = t_base + tile * TILE_T;
        __syncthreads();   // previous tile fully consumed before overwrite
        for (int idx = tid; idx < CC * TILE_T; idx += 256) {
            int c = idx / TILE_T, tt = idx - c * TILE_T;
            sX[c * TILE_T + tt] = x[(size_t)(b * CC + c) * TT_TOTAL + t0 + tt];
        }
        __syncthreads();
        // conv: acc[l][m] for rows o0+l, t = ts + 16*m
        float acc[4][7];
        for (int l = 0; l < 4; ++l)
            for (int m = 0; m < 7; ++m) acc[l][m] = bias_r[l];
        for (int c = 0; c < CC; ++c) {
            float w_r[4];
            for (int l = 0; l < 4; ++l)
                w_r[l] = (l < nrow) ? sW[(o0 + l) * CC + c] : 0.0f;
            for (int m = 0; m < 7; ++m) {
                int t = ts + (m << 4);
                if (t < TILE_T) {
                    float xv = sX[c * TILE_T + t];
                    for (int l = 0; l < 4; ++l) acc[l][m] += w_r[l] * xv;
                }
            }
        }
        for (int l = 0; l < nrow; ++l)
            for (int m = 0; m < 7; ++m) {
                int t = ts + (m << 4);
                if (t < TILE_T) sXC[(o0 + l) * 101 + t] = acc[l][m];
            }
        __syncthreads();
        // fp64 Grammian accumulation (upper-tri pairs, j-grouped by 2)
        for (int s = 0; s < nit; ++s) {
            const int i = ii[s], j0 = jj[s];
            const float* ri = &sXC[i * 101];
            const float* rj = &sXC[j0 * 101];
            if (j0 + 1 < CC) {
                const float* rj1 = &sXC[(j0 + 1) * 101];
                double a0 = acc0[s], a1 = acc1[s];
                for (int t = 0; t < TILE_T; ++t) {
                    double xi = (double)ri[t];
                    a0 += xi * (double)rj[t];
                    a1 += xi * (double)rj1[t];
                }
                acc0[s] = a0; acc1[s] = a1;
            } else {
                double a0 = acc0[s];
                for (int t = 0; t < TILE_T; ++t)
                    a0 += (double)ri[t] * (double)rj[t];
                acc0[s] = a0;
            }
        }
        if (tid < CC) {
            const float* rc = &sXC[tid * 101];
            for (int t = 0; t < TILE_T; ++t) macc += (double)rc[t];
        }
    }

    double* Sb = S + (size_t)(b * NPART + part) * VECN;
    for (int s = 0; s < nit; ++s) {
        int i = ii[s], j0 = jj[s];
        int base = i * CC - (i * (i - 1)) / 2;
        Sb[base + (j0 - i)] = acc0[s];
        if (j0 + 1 < CC) Sb[base + (j0 + 1 - i)] = acc1[s];
    }
    if (tid < CC) M[(size_t)(b * NPART + part) * 64 + tid] = macc;
}

// ---------------------------------------------------------------------------
// round-robin (circle method) pair schedule: 31 disjoint pairs, 61 rounds
// ---------------------------------------------------------------------------
__device__ __forceinline__ void pairPQ(int r, int k, int& p, int& q)
{
    if (k == 0) { p = 0; q = 1 + (r + 60) % 61; }
    else {
        p = 1 + (r + k - 1) % 61;
        q = 1 + (r + 60 - k) % 61;
    }
    if (p > q) { int t = p; p = q; q = t; }
}

__device__ __forceinline__ double waveSum(double v)
{
    for (int off = 32; off > 0; off >>= 1) v += __shfl_down(v, off, 64);
    return v;
}

// ---------------------------------------------------------------------------
// K2: assemble fp64 covariance, parallel cyclic Jacobi eigh, log-map,
//     triu-vectorize to fp32. grid = B, block = 256. LDS ~64 KB.
// ---------------------------------------------------------------------------
#define LDA 63   // row stride for sA/sV (odd -> decent bank spread for fp64)

__global__ __launch_bounds__(256) void k2_eig(
    const double* __restrict__ S, const double* __restrict__ M,
    float* __restrict__ vecout)
{
    const int b   = blockIdx.x;
    const int tid = threadIdx.x;

    __shared__ double sA[CC * LDA];
    __shared__ double sV[CC * LDA];
    __shared__ double sC[31], sSn[31];
    __shared__ double sMean[CC];
    __shared__ double lam[CC];
    __shared__ double sRedO[4], sRedD[4];
    __shared__ int    sDone;

    if (tid < CC) {
        double mm = 0.0;
        for (int p = 0; p < NPART; ++p) mm += M[(size_t)(b * NPART + p) * 64 + tid];
        sMean[tid] = mm / (double)TT_TOTAL;
    }
    __syncthreads();

    // assemble cov = (S - T*mean*mean^T)/(T-1) + 1e-3*I  (exactly symmetric)
    for (int pi = tid; pi < VECN; pi += 256) {
        int i = 0, rem = pi;
        while (rem >= CC - i) { rem -= (CC - i); ++i; }
        int j = i + rem;
        double s = 0.0;
        for (int p = 0; p < NPART; ++p) s += S[(size_t)(b * NPART + p) * VECN + pi];
        double covv = (s - (double)TT_TOTAL * sMean[i] * sMean[j]) / 1999.0;
        if (i == j) covv += 1e-3;
        sA[i * LDA + j] = covv;
        sA[j * LDA + i] = covv;
    }
    for (int idx = tid; idx < CC * CC; idx += 256) {
        int i = idx / CC, j = idx - i * CC;
        sV[i * LDA + j] = (i == j) ? 1.0 : 0.0;
    }
    __syncthreads();

    for (int sweep = 0; sweep < 16; ++sweep) {
        // convergence check: off^2 vs diag^2
        double po = 0.0, pd = 0.0;
        for (int pi = tid; pi < VECN; pi += 256) {
            int i = 0, rem = pi;
            while (rem >= CC - i) { rem -= (CC - i); ++i; }
            int j = i + rem;
            double v = sA[i * LDA + j];
            if (i == j) pd += v * v; else po += v * v;
        }
        po = waveSum(po); pd = waveSum(pd);
        if ((tid & 63) == 0) { sRedO[tid >> 6] = po; sRedD[tid >> 6] = pd; }
        __syncthreads();
        if (tid == 0) {
            double o = sRedO[0] + sRedO[1] + sRedO[2] + sRedO[3];
            double d = sRedD[0] + sRedD[1] + sRedD[2] + sRedD[3];
            sDone = (o <= 1e-25 * d + 1e-60) ? 1 : 0;
        }
        __syncthreads();
        if (sDone) break;

        for (int r = 0; r < 61; ++r) {
            if (tid < 31) {
                int p, q; pairPQ(r, tid, p, q);
                double app = sA[p * LDA + p];
                double aqq = sA[q * LDA + q];
                double apq = sA[p * LDA + q];
                double c = 1.0, s = 0.0;
                if (fabs(apq) > 1e-290) {
                    double th = (aqq - app) / (2.0 * apq);
                    double t  = 1.0 / (fabs(th) + sqrt(th * th + 1.0));
                    if (th < 0.0) t = -t;
                    c = 1.0 / sqrt(t * t + 1.0);
                    s = t * c;
                }
                sC[tid] = c; sSn[tid] = s;
            }
            __syncthreads();
            // row phase: B = J^T A
            for (int idx = tid; idx < 31 * CC; idx += 256) {
                int k = idx / CC, j = idx - k * CC;
                int p, q; pairPQ(r, k, p, q);
                double c = sC[k], s = sSn[k];
                double ap = sA[p * LDA + j], aq = sA[q * LDA + j];
                sA[p * LDA + j] = c * ap - s * aq;
                sA[q * LDA + j] = s * ap + c * aq;
            }
            __syncthreads();
            // col phase: A' = B J  and  V' = V J
            for (int idx = tid; idx < 2 * 31 * CC; idx += 256) {
                int half = idx / (31 * CC);
                int rem2 = idx - half * (31 * CC);
                int k = rem2 / CC, i = rem2 - k * CC;
                int p, q; pairPQ(r, k, p, q);
                double c = sC[k], s = sSn[k];
                double* Mx = half ? sV : sA;
                double ap = Mx[i * LDA + p], aq = Mx[i * LDA + q];
                Mx[i * LDA + p] = c * ap - s * aq;
                Mx[i * LDA + q] = s * ap + c * aq;
            }
            __syncthreads();
        }
    }

    // log-map reconstruction: log_cov = V diag(log max(lam,1e-6)) V^T
    if (tid < CC) lam[tid] = log(fmax(sA[tid * LDA + tid], 1e-6));
    __syncthreads();
    for (int idx = tid; idx < CC * CC; idx += 256) {
        int i = idx / CC, k = idx - i * CC;
        sA[i * LDA + k] = sV[i * LDA + k] * lam[k];   // W = V * diag(lam)
    }
    __syncthreads();
    float* vb = vecout + (size_t)b * VECN;
    for (int pi = tid; pi < VECN; pi += 256) {
        int i = 0, rem = pi;
        while (rem >= CC - i) { rem -= (CC - i); ++i; }
        int j = i + rem;
        const double* wi = &sA[i * LDA];
        const double* vj = &sV[j * LDA];
        double acc = 0.0;
        for (int k = 0; k < CC; ++k) acc += wi[k] * vj[k];
        vb[pi] = (float)acc;
    }
}

// ---------------------------------------------------------------------------
// K3: feat = relu(vec @ proj_w^T + proj_b); logits = feat @ head_w^T + head_b
// grid = B, block = 64
// ---------------------------------------------------------------------------
__global__ __launch_bounds__(64) void k3_mlp(
    const float* __restrict__ vecin, const float* __restrict__ pw,
    const float* __restrict__ pb, const float* __restrict__ hw,
    const float* __restrict__ hb, float* __restrict__ out)
{
    const int b = blockIdx.x;
    const int tid = threadIdx.x;
    __shared__ float sv[VECN];
    __shared__ float sf[HID];
    for (int k = tid; k < VECN; k += 64) sv[k] = vecin[(size_t)b * VECN + k];
    __syncthreads();
    float acc = pb[tid];
    const float* w = pw + (size_t)tid * VECN;
    for (int k = 0; k < VECN; ++k) acc += sv[k] * w[k];
    sf[tid] = fmaxf(acc, 0.0f);
    __syncthreads();
    if (tid < NCLS) {
        float o = hb[tid];
        for (int h = 0; h < HID; ++h) o += sf[h] * hw[tid * HID + h];
        out[b * NCLS + tid] = o;
    }
}

// ---------------------------------------------------------------------------
extern "C" void kernel_launch(void* const* d_in, const int* in_sizes, int n_in,
                              void* d_out, int out_size, void* d_ws, size_t ws_size,
                              hipStream_t stream)
{
    const float* x  = (const float*)d_in[0];
    const float* cw = (const float*)d_in[1];
    const float* cb = (const float*)d_in[2];
    const float* pw = (const float*)d_in[3];
    const float* pb = (const float*)d_in[4];
    const float* hw = (const float*)d_in[5];
    const float* hb = (const float*)d_in[6];
    float* out = (float*)d_out;

    // workspace layout (doubles first):
    //   S   : [B*NPART][VECN] fp64   (~16.0 MB)
    //   M   : [B*NPART][64]   fp64   (~0.5 MB)
    //   vec : [B][VECN]       fp32   (~2.0 MB)
    double* S = (double*)d_ws;
    double* M = S + (size_t)BB * NPART * VECN;
    float* vec = (float*)(M + (size_t)BB * NPART * 64);

    dim3 g1(BB, NPART);
    k1_cov<<<g1, 256, 0, stream>>>(x, cw, cb, S, M);
    k2_eig<<<BB, 256, 0, stream>>>(S, M, vec);
    k3_mlp<<<BB, 64, 0, stream>>>(vec, pw, pb, hw, hb, out);
}

// Round 2
// 1577.282 us; speedup vs baseline: 1.9036x; 1.9036x over previous
//
#include <hip/hip_runtime.h>
#include <math.h>

// Problem constants
#define CC 62
#define TT_TOTAL 2000
#define BB 256
#define VECN 1953          // C*(C+1)/2
#define HID 64
#define NCLS 3
#define NPART 4            // t-parts for covariance partials
#define TCHUNK 500         // TT_TOTAL / NPART
#define TILE_T 100         // t-tile inside a part (5 tiles per part)
#define NTILES 5
#define NPAIR2 992         // sum_i ceil((62-i)/2)

// ---------------------------------------------------------------------------
// K1: conv1d(k=1) in fp32 + fp64 partial Grammian S = sum_t xc xc^T and
//     partial sums m = sum_t xc over a 500-sample t-chunk.
// grid = (B, NPART), block = 256
// ---------------------------------------------------------------------------
__global__ __launch_bounds__(256) void k1_cov(
    const float* __restrict__ x, const float* __restrict__ cw,
    const float* __restrict__ cb, double* __restrict__ S,
    double* __restrict__ M)
{
    const int b    = blockIdx.x;
    const int part = blockIdx.y;
    const int tid  = threadIdx.x;

    __shared__ float sW[CC * CC];          // 15376 B
    __shared__ float sX[CC * TILE_T];
    __shared__ float sXC[CC * 101];

    for (int idx = tid; idx < CC * CC; idx += 256) sW[idx] = cw[idx];

    const int oq = tid >> 4;          // 0..15
    const int ts = tid & 15;          // 0..15
    const int o0 = oq * 4;
    const int nrow = (CC - o0) < 4 ? (CC - o0) : 4;   // 4 or 2
    float bias_r[4];
    for (int l = 0; l < 4; ++l) bias_r[l] = (l < nrow) ? cb[o0 + l] : 0.0f;

    int ii[4], jj[4];
    double acc0[4], acc1[4];
    int nit = 0;
    for (int s = 0; s < 4; ++s) {
        int item = tid + s * 256;
        if (item < NPAIR2) {
            int rem = item, i = 0;
            while (true) { int cnt = (63 - i) >> 1; if (rem < cnt) break; rem -= cnt; ++i; }
            ii[s] = i; jj[s] = i + 2 * rem;
            acc0[s] = 0.0; acc1[s] = 0.0;
            nit = s + 1;
        }
    }
    double macc = 0.0;

    const int t_base = part * TCHUNK;
    for (int tile = 0; tile < NTILES; ++tile) {
        const int t0 = t_base + tile * TILE_T;
        __syncthreads();
        for (int idx = tid; idx < CC * TILE_T; idx += 256) {
            int c = idx / TILE_T, tt = idx - c * TILE_T;
            sX[c * TILE_T + tt] = x[(size_t)(b * CC + c) * TT_TOTAL + t0 + tt];
        }
        __syncthreads();
        float acc[4][7];
        for (int l = 0; l < 4; ++l)
            for (int m = 0; m < 7; ++m) acc[l][m] = bias_r[l];
        for (int c = 0; c < CC; ++c) {
            float w_r[4];
            for (int l = 0; l < 4; ++l)
                w_r[l] = (l < nrow) ? sW[(o0 + l) * CC + c] : 0.0f;
            for (int m = 0; m < 7; ++m) {
                int t = ts + (m << 4);
                if (t < TILE_T) {
                    float xv = sX[c * TILE_T + t];
                    for (int l = 0; l < 4; ++l) acc[l][m] += w_r[l] * xv;
                }
            }
        }
        for (int l = 0; l < nrow; ++l)
            for (int m = 0; m < 7; ++m) {
                int t = ts + (m << 4);
                if (t < TILE_T) sXC[(o0 + l) * 101 + t] = acc[l][m];
            }
        __syncthreads();
        for (int s = 0; s < nit; ++s) {
            const int i = ii[s], j0 = jj[s];
            const float* ri = &sXC[i * 101];
            const float* rj = &sXC[j0 * 101];
            if (j0 + 1 < CC) {
                const float* rj1 = &sXC[(j0 + 1) * 101];
                double a0 = acc0[s], a1 = acc1[s];
                for (int t = 0; t < TILE_T; ++t) {
                    double xi = (double)ri[t];
                    a0 += xi * (double)rj[t];
                    a1 += xi * (double)rj1[t];
                }
                acc0[s] = a0; acc1[s] = a1;
            } else {
                double a0 = acc0[s];
                for (int t = 0; t < TILE_T; ++t)
                    a0 += (double)ri[t] * (double)rj[t];
                acc0[s] = a0;
            }
        }
        if (tid < CC) {
            const float* rc = &sXC[tid * 101];
            for (int t = 0; t < TILE_T; ++t) macc += (double)rc[t];
        }
    }

    double* Sb = S + (size_t)(b * NPART + part) * VECN;
    for (int s = 0; s < nit; ++s) {
        int i = ii[s], j0 = jj[s];
        int base = i * CC - (i * (i - 1)) / 2;
        Sb[base + (j0 - i)] = acc0[s];
        if (j0 + 1 < CC) Sb[base + (j0 + 1 - i)] = acc1[s];
    }
    if (tid < CC) M[(size_t)(b * NPART + part) * 64 + tid] = macc;
}

// ---------------------------------------------------------------------------
// round-robin (circle method) pair schedule: 31 disjoint pairs, 61 rounds
// ---------------------------------------------------------------------------
__device__ __forceinline__ void pairPQ(int r, int k, int& p, int& q)
{
    if (k == 0) { p = 0; q = 1 + (r + 60) % 61; }
    else {
        p = 1 + (r + k - 1) % 61;
        q = 1 + (r + 60 - k) % 61;
    }
    if (p > q) { int t = p; p = q; q = t; }
}

__device__ __forceinline__ double waveSum(double v)
{
    for (int off = 32; off > 0; off >>= 1) v += __shfl_down(v, off, 64);
    return v;
}

// ---------------------------------------------------------------------------
// K2: assemble fp64 covariance, parallel cyclic Jacobi eigh (2x2-block fused
//     rotations, symmetric-half updates), log-map, triu-vectorize to fp32.
// grid = B, block = 512 (8 waves for latency hiding; grid is pinned at B=256
// blocks = 1/CU, so waves-per-block is the only occupancy lever).
// ---------------------------------------------------------------------------
#define LDA 63       // row stride (doubles) for sA/sV
#define NROT 31
#define NT_A 496     // 31 diag blocks + 465 strict-upper blocks
#define NT_TOT 1457  // + 961 V tasks (31 row-pairs x 31 col-pairs)

__global__ __launch_bounds__(512) void k2_eig(
    const double* __restrict__ S, const double* __restrict__ M,
    float* __restrict__ vecout)
{
    const int b   = blockIdx.x;
    const int tid = threadIdx.x;

    __shared__ double sA[CC * LDA];
    __shared__ double sV[CC * LDA];
    __shared__ double sC[NROT], sS[NROT];
    __shared__ int    sPp[NROT], sQq[NROT];
    __shared__ double sMean[64];
    __shared__ double lam[64];
    __shared__ double sRed[16];
    __shared__ int    sDone;

    // --- per-thread static task list (round-invariant): type 0=diag A-block,
    //     1=strict-upper A-block (kp<kq), 2=V row-pair block
    int tTy[3], tIa[3], tIb[3], nT = 0;
    for (int task = tid; task < NT_TOT; task += 512) {
        if (task < NROT) { tTy[nT] = 0; tIa[nT] = task; tIb[nT] = task; }
        else if (task < NT_A) {
            int a = task - NROT, kp = 0;
            while (a >= 30 - kp) { a -= 30 - kp; ++kp; }
            tTy[nT] = 1; tIa[nT] = kp; tIb[nT] = kp + 1 + a;
        } else {
            int v = task - NT_A;
            int rm = v / NROT;
            tTy[nT] = 2; tIa[nT] = rm; tIb[nT] = v - rm * NROT;
        }
        ++nT;
    }

    if (tid < CC) {
        double mm = 0.0;
        for (int p = 0; p < NPART; ++p) mm += M[(size_t)(b * NPART + p) * 64 + tid];
        sMean[tid] = mm / (double)TT_TOTAL;
    }
    __syncthreads();

    // assemble cov = (S - T*mean*mean^T)/(T-1) + 1e-3*I  (exactly symmetric)
    for (int pi = tid; pi < VECN; pi += 512) {
        int i = 0, rem = pi;
        while (rem >= CC - i) { rem -= (CC - i); ++i; }
        int j = i + rem;
        double s = 0.0;
        for (int p = 0; p < NPART; ++p) s += S[(size_t)(b * NPART + p) * VECN + pi];
        double covv = (s - (double)TT_TOTAL * sMean[i] * sMean[j]) / 1999.0;
        if (i == j) covv += 1e-3;
        sA[i * LDA + j] = covv;
        sA[j * LDA + i] = covv;
    }
    for (int idx = tid; idx < CC * CC; idx += 512) {
        int i = idx / CC, j = idx - i * CC;
        sV[i * LDA + j] = (i == j) ? 1.0 : 0.0;
    }
    __syncthreads();

    for (int sweep = 0; sweep < 14; ++sweep) {
        // convergence: off^2 vs diag^2
        double po = 0.0, pd = 0.0;
        for (int pi = tid; pi < VECN; pi += 512) {
            int i = 0, rem = pi;
            while (rem >= CC - i) { rem -= (CC - i); ++i; }
            int j = i + rem;
            double v = sA[i * LDA + j];
            if (i == j) pd += v * v; else po += v * v;
        }
        po = waveSum(po); pd = waveSum(pd);
        if ((tid & 63) == 0) { sRed[tid >> 6] = po; sRed[8 + (tid >> 6)] = pd; }
        __syncthreads();
        if (tid == 0) {
            double o = 0.0, d = 0.0;
            for (int w = 0; w < 8; ++w) { o += sRed[w]; d += sRed[8 + w]; }
            sDone = (o <= 1e-20 * d + 1e-60) ? 1 : 0;
        }
        __syncthreads();
        if (sDone) break;

        for (int r = 0; r < 61; ++r) {
            if (tid < NROT) {
                int p, q; pairPQ(r, tid, p, q);
                sPp[tid] = p; sQq[tid] = q;
                double app = sA[p * LDA + p];
                double aqq = sA[q * LDA + q];
                double apq = sA[p * LDA + q];
                double c = 1.0, s = 0.0;
                if (fabs(apq) > 1e-290) {
                    double th = (aqq - app) / (2.0 * apq);
                    double t  = 1.0 / (fabs(th) + sqrt(th * th + 1.0));
                    if (th < 0.0) t = -t;
                    c = 1.0 / sqrt(t * t + 1.0);
                    s = t * c;
                }
                sC[tid] = c; sS[tid] = s;
            }
            __syncthreads();
            for (int u = 0; u < nT; ++u) {
                int ty = tTy[u];
                if (ty == 1) {
                    // strict-upper 2x2 block: rows (p,q)=pair kp, cols (r2,s2)=pair kq
                    int kp = tIa[u], kq = tIb[u];
                    int p = sPp[kp], q = sQq[kp], r2 = sPp[kq], s2 = sQq[kq];
                    double cp = sC[kp], sp = sS[kp], cq = sC[kq], sq = sS[kq];
                    double a00 = sA[p * LDA + r2], a01 = sA[p * LDA + s2];
                    double a10 = sA[q * LDA + r2], a11 = sA[q * LDA + s2];
                    double b00 = cp * a00 - sp * a10, b01 = cp * a01 - sp * a11;
                    double b10 = sp * a00 + cp * a10, b11 = sp * a01 + cp * a11;
                    double c00 = cq * b00 - sq * b01, c01 = sq * b00 + cq * b01;
                    double c10 = cq * b10 - sq * b11, c11 = sq * b10 + cq * b11;
                    sA[p * LDA + r2] = c00; sA[p * LDA + s2] = c01;
                    sA[q * LDA + r2] = c10; sA[q * LDA + s2] = c11;
                    sA[r2 * LDA + p] = c00; sA[s2 * LDA + p] = c01;
                    sA[r2 * LDA + q] = c10; sA[s2 * LDA + q] = c11;
                } else if (ty == 0) {
                    // diagonal block of pair k: annihilates (p,q)
                    int k = tIa[u];
                    int p = sPp[k], q = sQq[k];
                    double c = sC[k], s = sS[k];
                    double app = sA[p * LDA + p], apq = sA[p * LDA + q], aqq = sA[q * LDA + q];
                    double t0 = c * app - s * apq, t1 = c * apq - s * aqq;
                    double t2 = s * app + c * apq, t3 = s * apq + c * aqq;
                    sA[p * LDA + p] = c * t0 - s * t1;
                    sA[q * LDA + q] = s * t2 + c * t3;
                    sA[p * LDA + q] = 0.0; sA[q * LDA + p] = 0.0;
                } else {
                    // V block: rows (2rm, 2rm+1), cols (p2,q2)=pair kq (right rot only)
                    int rm = tIa[u], kq = tIb[u];
                    int i0 = rm * 2, p2 = sPp[kq], q2 = sQq[kq];
                    double c = sC[kq], s = sS[kq];
                    double v00 = sV[i0 * LDA + p2],      v01 = sV[i0 * LDA + q2];
                    double v10 = sV[(i0 + 1) * LDA + p2], v11 = sV[(i0 + 1) * LDA + q2];
                    sV[i0 * LDA + p2]       = c * v00 - s * v01;
                    sV[i0 * LDA + q2]       = s * v00 + c * v01;
                    sV[(i0 + 1) * LDA + p2] = c * v10 - s * v11;
                    sV[(i0 + 1) * LDA + q2] = s * v10 + c * v11;
                }
            }
            __syncthreads();
        }
    }

    // log-map reconstruction: log_cov = V diag(log max(lam,1e-6)) V^T
    if (tid < CC) lam[tid] = log(fmax(sA[tid * LDA + tid], 1e-6));
    __syncthreads();
    for (int idx = tid; idx < CC * CC; idx += 512) {
        int i = idx / CC, k = idx - i * CC;
        sA[i * LDA + k] = sV[i * LDA + k] * lam[k];   // W = V * diag(lam)
    }
    __syncthreads();
    float* vb = vecout + (size_t)b * VECN;
    for (int pi = tid; pi < VECN; pi += 512) {
        int i = 0, rem = pi;
        while (rem >= CC - i) { rem -= (CC - i); ++i; }
        int j = i + rem;
        const double* wi = &sA[i * LDA];
        const double* vj = &sV[j * LDA];
        double acc = 0.0;
        for (int k = 0; k < CC; ++k) acc += wi[k] * vj[k];
        vb[pi] = (float)acc;
    }
}

// ---------------------------------------------------------------------------
// K3: feat = relu(vec @ proj_w^T + proj_b); logits = feat @ head_w^T + head_b
// grid = B, block = 64
// ---------------------------------------------------------------------------
__global__ __launch_bounds__(64) void k3_mlp(
    const float* __restrict__ vecin, const float* __restrict__ pw,
    const float* __restrict__ pb, const float* __restrict__ hw,
    const float* __restrict__ hb, float* __restrict__ out)
{
    const int b = blockIdx.x;
    const int tid = threadIdx.x;
    __shared__ float sv[VECN];
    __shared__ float sf[HID];
    for (int k = tid; k < VECN; k += 64) sv[k] = vecin[(size_t)b * VECN + k];
    __syncthreads();
    float acc = pb[tid];
    const float* w = pw + (size_t)tid * VECN;
    for (int k = 0; k < VECN; ++k) acc += sv[k] * w[k];
    sf[tid] = fmaxf(acc, 0.0f);
    __syncthreads();
    if (tid < NCLS) {
        float o = hb[tid];
        for (int h = 0; h < HID; ++h) o += sf[h] * hw[tid * HID + h];
        out[b * NCLS + tid] = o;
    }
}

// ---------------------------------------------------------------------------
extern "C" void kernel_launch(void* const* d_in, const int* in_sizes, int n_in,
                              void* d_out, int out_size, void* d_ws, size_t ws_size,
                              hipStream_t stream)
{
    const float* x  = (const float*)d_in[0];
    const float* cw = (const float*)d_in[1];
    const float* cb = (const float*)d_in[2];
    const float* pw = (const float*)d_in[3];
    const float* pb = (const float*)d_in[4];
    const float* hw = (const float*)d_in[5];
    const float* hb = (const float*)d_in[6];
    float* out = (float*)d_out;

    double* S = (double*)d_ws;
    double* M = S + (size_t)BB * NPART * VECN;
    float* vec = (float*)(M + (size_t)BB * NPART * 64);

    dim3 g1(BB, NPART);
    k1_cov<<<g1, 256, 0, stream>>>(x, cw, cb, S, M);
    k2_eig<<<BB, 512, 0, stream>>>(S, M, vec);
    k3_mlp<<<BB, 64, 0, stream>>>(vec, pw, pb, hw, hb, out);
}

// Round 3
// 1212.324 us; speedup vs baseline: 2.4767x; 1.3010x over previous
//
#include <hip/hip_runtime.h>
#include <math.h>

// Problem constants
#define CC 62
#define TT 2000
#define BB 256
#define VECN 1953          // C*(C+1)/2
#define HID 64
#define NCLS 3
#define NPART 4            // t-parts for Grammian partials
#define TCHUNK 500         // TT / NPART
#define TTILE 50           // t-tile
#define NTILES 10          // TCHUNK / TTILE
#define LDT 66             // sXT row stride (doubles), 66*8B -> bank offset 4/t
#define LDG 66             // G column stride (doubles)
#define NG 31              // disjoint pairs per round

__device__ __forceinline__ void decodePi(int pi, int& i, int& j)
{
    int ii = 0, rem = pi;
    while (rem >= CC - ii) { rem -= (CC - ii); ++ii; }
    i = ii; j = ii + rem;
}

// round-robin (circle method) pair schedule: 31 disjoint pairs, 61 rounds
__device__ __forceinline__ void pairPQ(int r, int k, int& p, int& q)
{
    if (k == 0) { p = 0; q = 1 + (r + 60) % 61; }
    else {
        p = 1 + (r + k - 1) % 61;
        q = 1 + (r + 60 - k) % 61;
    }
    if (p > q) { int t = p; p = q; q = t; }
}

// ---------------------------------------------------------------------------
// K1: raw-x fp64 partial Grammian S = sum_t x x^T (upper-tri packed) and
//     partial sums m = sum_t x over a 500-sample t-chunk. NO conv here:
//     cov(Wx+b) = W cov(x) W^T is applied in k2's prologue.
// grid = (B, NPART), block = 192 (136 Grammian threads: 16 row-groups of 4,
// 4x4 register tile per thread -> 2 fp64 FMA per LDS load).
// ---------------------------------------------------------------------------
__global__ __launch_bounds__(192) void k1_gram(
    const float* __restrict__ x, double* __restrict__ S,
    double* __restrict__ M)
{
    const int b = blockIdx.x, part = blockIdx.y, tid = threadIdx.x;

    __shared__ double sXT[TTILE * LDT];   // [t][c], c padded to 64, 26.4KB
    __shared__ double sMP[192];

    // loader mapping: 3 threads per channel row
    const int lc = tid / 3, lsub = tid - lc * 3;
    const int lt0 = (lsub == 0) ? 0 : (lsub == 1 ? 17 : 34);
    const int lt1 = (lsub == 0) ? 17 : (lsub == 1 ? 34 : 50);
    const bool loader = (lc < CC);

    // Grammian mapping: thread u<136 -> group-pair (gi<=gj) of 16 groups of 4
    int gi = 0, gj = 0;
    if (tid < 136) {
        int g = 0, rem = tid;
        while (rem >= 16 - g) { rem -= (16 - g); ++g; }
        gi = g; gj = g + rem;
    }
    const bool gram = (tid < 136);
    const int c0 = 4 * gi, c1 = 4 * gj;
    int ph = tid; while (ph >= TTILE) ph -= TTILE;   // bank-stagger phase

    double acc[4][4];
#pragma unroll
    for (int a = 0; a < 4; ++a)
#pragma unroll
        for (int c = 0; c < 4; ++c) acc[a][c] = 0.0;
    double macc = 0.0;

    // zero pad channels 62,63 (never written by loaders, stay 0)
    if (tid < TTILE) { sXT[tid * LDT + 62] = 0.0; sXT[tid * LDT + 63] = 0.0; }

    const float* xb = x + (size_t)b * CC * TT;
    const int tbase = part * TCHUNK;

    for (int tile = 0; tile < NTILES; ++tile) {
        const int t0 = tbase + tile * TTILE;
        __syncthreads();   // previous tile consumed (also covers pad init)
        if (loader) {
            const float* xr = xb + (size_t)lc * TT + t0;
            for (int t = lt0; t < lt1; ++t) {
                float v = xr[t];
                macc += (double)v;
                sXT[t * LDT + lc] = (double)v;
            }
        }
        __syncthreads();
        if (gram) {
            for (int it = 0; it < TTILE; ++it) {
                int t = it + ph; if (t >= TTILE) t -= TTILE;
                const double* rowt = &sXT[t * LDT];
                double a0 = rowt[c0], a1 = rowt[c0 + 1], a2 = rowt[c0 + 2], a3 = rowt[c0 + 3];
                double b0 = rowt[c1], b1 = rowt[c1 + 1], b2 = rowt[c1 + 2], b3 = rowt[c1 + 3];
                acc[0][0] += a0 * b0; acc[0][1] += a0 * b1; acc[0][2] += a0 * b2; acc[0][3] += a0 * b3;
                acc[1][0] += a1 * b0; acc[1][1] += a1 * b1; acc[1][2] += a1 * b2; acc[1][3] += a1 * b3;
                acc[2][0] += a2 * b0; acc[2][1] += a2 * b1; acc[2][2] += a2 * b2; acc[2][3] += a2 * b3;
                acc[3][0] += a3 * b0; acc[3][1] += a3 * b1; acc[3][2] += a3 * b2; acc[3][3] += a3 * b3;
            }
        }
    }
    __syncthreads();
    sMP[tid] = macc;
    __syncthreads();
    if (tid < CC)
        M[((size_t)b * NPART + part) * 64 + tid] =
            sMP[tid * 3] + sMP[tid * 3 + 1] + sMP[tid * 3 + 2];

    if (gram) {
        double* Sb = S + ((size_t)b * NPART + part) * VECN;
#pragma unroll
        for (int a = 0; a < 4; ++a) {
            int i = c0 + a;
#pragma unroll
            for (int c = 0; c < 4; ++c) {
                int j = c1 + c;
                if (j < CC && i <= j) {
                    int pi = i * CC - (i * (i - 1)) / 2 + (j - i);
                    Sb[pi] = acc[a][c];
                }
            }
        }
    }
}

// ---------------------------------------------------------------------------
// K2: assemble cov_x (packed), A = W cov_x W^T + eps I, then ONE-SIDED Jacobi
//     on G = A (column rotations only, cached norms, no V matrix), then
//     log_cov = G diag(log(lam)/lam^2) G^T, triu-vectorize to fp32.
// grid = B, block = 512. 1 barrier per round. LDS ~61.6KB.
// ---------------------------------------------------------------------------
__global__ __launch_bounds__(512) void k2_eig(
    const double* __restrict__ S, const double* __restrict__ M,
    const float* __restrict__ cw, float* __restrict__ vecout)
{
    const int b = blockIdx.x, tid = threadIdx.x;

    __shared__ double sG[CC * LDG];    // column-major, rows padded to 64 w/ 0
    __shared__ double sC[VECN];        // packed upper-tri cov_x
    __shared__ double sU[8 * 64];      // W*C*W^T chunk buffer
    __shared__ double sNorm[64];
    __shared__ double sD[64];
    __shared__ double sMean[64];
    __shared__ int    sPair[61 * NG];
    __shared__ double sRed[8];
    __shared__ int    sDone;

    // precompute full pair schedule (once)
    for (int e = tid; e < 61 * NG; e += 512) {
        int r = e / NG, k = e - r * NG;
        int p, q; pairPQ(r, k, p, q);
        sPair[e] = p | (q << 8);
    }
    if (tid < CC) {
        double mm = 0.0;
        for (int p = 0; p < NPART; ++p) mm += M[((size_t)b * NPART + p) * 64 + tid];
        sMean[tid] = mm / (double)TT;
    }
    for (int e = tid; e < CC * LDG; e += 512) sG[e] = 0.0;
    __syncthreads();

    // packed cov_x = (S - T m m^T)/(T-1)
    for (int pi = tid; pi < VECN; pi += 512) {
        int i, j; decodePi(pi, i, j);
        double s = 0.0;
        for (int p = 0; p < NPART; ++p) s += S[((size_t)b * NPART + p) * VECN + pi];
        sC[pi] = (s - (double)TT * sMean[i] * sMean[j]) / 1999.0;
    }
    __syncthreads();

    // A = W C W^T + eps I, chunks of 8 output columns
    const int jj = tid >> 6, kk = tid & 63;
    for (int j0 = 0; j0 < CC; j0 += 8) {
        const int j = j0 + jj;
        if (kk < CC && j < CC) {
            const float* wr = cw + j * CC;
            double a = 0.0; int idx = kk;
            for (int l = 0; l < kk; ++l) { a += sC[idx] * (double)wr[l]; idx += 61 - l; }
            for (int l = kk; l < CC; ++l) { a += sC[idx] * (double)wr[l]; idx += 1; }
            sU[jj * 64 + kk] = a;    // u_j[k] = (C w_j)[k]
        }
        __syncthreads();
        const int i = kk;
        if (i < CC && j < CC && i <= j) {
            const float* wi = cw + i * CC;
            double a = (i == j) ? 1e-3 : 0.0;
            for (int l = 0; l < CC; ++l) a += (double)wi[l] * sU[jj * 64 + l];
            sG[j * LDG + i] = a;
            sG[i * LDG + j] = a;
        }
        __syncthreads();
    }

    // initial column norms n_k = ||g_k||^2
    if (tid < CC) {
        const double* col = &sG[tid * LDG];
        double n = 0.0;
        for (int i2 = 0; i2 < CC; ++i2) n += col[i2] * col[i2];
        sNorm[tid] = n;
    }
    __syncthreads();

    // one-sided Jacobi: group g (16 threads) handles pair g each round;
    // thread lt handles rows lt, lt+16, lt+32, lt+48 (incl. zero pad rows)
    const int g = tid >> 4, lt = tid & 15;
    const bool act = (g < NG);
    const int i0 = lt, i1 = lt + 16, i2 = lt + 32, i3 = lt + 48;

    for (int sweep = 0; sweep < 16; ++sweep) {
        double mx = 0.0;
        for (int r = 0; r < 61; ++r) {
            if (act) {
                int pq = sPair[r * NG + g];
                int p = pq & 255, q = pq >> 8;
                double* gp = &sG[p * LDG];
                double* gq = &sG[q * LDG];
                double a0 = gp[i0], a1 = gp[i1], a2 = gp[i2], a3 = gp[i3];
                double b0 = gq[i0], b1 = gq[i1], b2 = gq[i2], b3 = gq[i3];
                double d = a0 * b0 + a1 * b1 + a2 * b2 + a3 * b3;
                d += __shfl_xor(d, 8, 16);
                d += __shfl_xor(d, 4, 16);
                d += __shfl_xor(d, 2, 16);
                d += __shfl_xor(d, 1, 16);
                double np = sNorm[p], nq = sNorm[q];
                double d2 = d * d, prod = np * nq;
                mx = fmax(mx, (d2 > prod * 1e-16) ? 1.0 : 0.0);
                if (d2 > prod * 1e-30) {
                    double th = (nq - np) / (2.0 * d);
                    double t = 1.0 / (fabs(th) + sqrt(th * th + 1.0));
                    if (th < 0.0) t = -t;
                    double c = 1.0 / sqrt(t * t + 1.0);
                    double sn = t * c;
                    gp[i0] = c * a0 - sn * b0; gp[i1] = c * a1 - sn * b1;
                    gp[i2] = c * a2 - sn * b2; gp[i3] = c * a3 - sn * b3;
                    gq[i0] = sn * a0 + c * b0; gq[i1] = sn * a1 + c * b1;
                    gq[i2] = sn * a2 + c * b2; gq[i3] = sn * a3 + c * b3;
                    if (lt == 0) { sNorm[p] = np - t * d; sNorm[q] = nq + t * d; }
                }
            }
            __syncthreads();
        }
        // converged when no pair this sweep had |d| > 1e-8*sqrt(np*nq)
        for (int off = 32; off; off >>= 1) mx = fmax(mx, __shfl_xor(mx, off, 64));
        if ((tid & 63) == 0) sRed[tid >> 6] = mx;
        __syncthreads();
        if (tid == 0) {
            double m2 = 0.0;
            for (int w = 0; w < 8; ++w) m2 = fmax(m2, sRed[w]);
            sDone = (m2 < 0.5) ? 1 : 0;
        }
        __syncthreads();
        if (sDone) break;
    }

    // lam_k^2 = ||g_k||^2 ; d_k = log(max(lam,1e-6))/lam^2
    if (tid < CC) {
        const double* col = &sG[tid * LDG];
        double n = 0.0;
        for (int i5 = 0; i5 < CC; ++i5) n += col[i5] * col[i5];
        double lamv = sqrt(n);
        sD[tid] = log(fmax(lamv, 1e-6)) / n;
    }
    __syncthreads();

    float* vb = vecout + (size_t)b * VECN;
    for (int pi = tid; pi < VECN; pi += 512) {
        int i, j; decodePi(pi, i, j);
        double a = 0.0;
        for (int k2 = 0; k2 < CC; ++k2)
            a += sD[k2] * sG[k2 * LDG + i] * sG[k2 * LDG + j];
        vb[pi] = (float)a;
    }
}

// ---------------------------------------------------------------------------
// K3: feat = relu(vec @ proj_w^T + proj_b); logits = feat @ head_w^T + head_b
// grid = B, block = 64
// ---------------------------------------------------------------------------
__global__ __launch_bounds__(64) void k3_mlp(
    const float* __restrict__ vecin, const float* __restrict__ pw,
    const float* __restrict__ pb, const float* __restrict__ hw,
    const float* __restrict__ hb, float* __restrict__ out)
{
    const int b = blockIdx.x;
    const int tid = threadIdx.x;
    __shared__ float sv[VECN];
    __shared__ float sf[HID];
    for (int k = tid; k < VECN; k += 64) sv[k] = vecin[(size_t)b * VECN + k];
    __syncthreads();
    float acc = pb[tid];
    const float* w = pw + (size_t)tid * VECN;
    for (int k = 0; k < VECN; ++k) acc += sv[k] * w[k];
    sf[tid] = fmaxf(acc, 0.0f);
    __syncthreads();
    if (tid < NCLS) {
        float o = hb[tid];
        for (int h = 0; h < HID; ++h) o += sf[h] * hw[tid * HID + h];
        out[b * NCLS + tid] = o;
    }
}

// ---------------------------------------------------------------------------
extern "C" void kernel_launch(void* const* d_in, const int* in_sizes, int n_in,
                              void* d_out, int out_size, void* d_ws, size_t ws_size,
                              hipStream_t stream)
{
    const float* x  = (const float*)d_in[0];
    const float* cw = (const float*)d_in[1];
    // d_in[2] = conv bias: cancels in covariance, unused
    const float* pw = (const float*)d_in[3];
    const float* pb = (const float*)d_in[4];
    const float* hw = (const float*)d_in[5];
    const float* hb = (const float*)d_in[6];
    float* out = (float*)d_out;

    // workspace: S [B*NPART][VECN] fp64 (16MB), M [B*NPART][64] fp64 (0.5MB),
    //            vec [B][VECN] fp32 (2MB)
    double* S = (double*)d_ws;
    double* M = S + (size_t)BB * NPART * VECN;
    float* vec = (float*)(M + (size_t)BB * NPART * 64);

    dim3 g1(BB, NPART);
    k1_gram<<<g1, 192, 0, stream>>>(x, S, M);
    k2_eig<<<BB, 512, 0, stream>>>(S, M, cw, vec);
    k3_mlp<<<BB, 64, 0, stream>>>(vec, pw, pb, hw, hb, out);
}

// Round 4
// 1095.452 us; speedup vs baseline: 2.7409x; 1.1067x over previous
//
#include <hip/hip_runtime.h>
#include <math.h>

// Problem constants
#define CC 62
#define TT 2000
#define BB 256
#define VECN 1953          // C*(C+1)/2
#define HID 64
#define NCLS 3
#define NPART 4            // t-parts for Grammian partials
#define TCHUNK 500         // TT / NPART
#define TTILE 50           // t-tile
#define NTILES 10          // TCHUNK / TTILE
#define LDT 66             // sXT row stride (doubles)
#define LDG 66             // G column stride (doubles), cols 16B-aligned
#define NG 31              // disjoint pairs per round

__device__ __forceinline__ void decodePi(int pi, int& i, int& j)
{
    int ii = 0, rem = pi;
    while (rem >= CC - ii) { rem -= (CC - ii); ++ii; }
    i = ii; j = ii + rem;
}

// round-robin (circle method) pair schedule: 31 disjoint pairs, 61 rounds
__device__ __forceinline__ void pairPQ(int r, int k, int& p, int& q)
{
    if (k == 0) { p = 0; q = 1 + (r + 60) % 61; }
    else {
        p = 1 + (r + k - 1) % 61;
        q = 1 + (r + 60 - k) % 61;
    }
    if (p > q) { int t = p; p = q; q = t; }
}

// ---------------------------------------------------------------------------
// K1: raw-x fp64 partial Grammian S = sum_t x x^T (upper-tri packed) and
//     partial sums m = sum_t x over a 500-sample t-chunk. NO conv here:
//     cov(Wx+b) = W cov(x) W^T is applied in k2's prologue.
// grid = (B, NPART), block = 192. Gram threads (136) read the SAME t-row
// (broadcast-friendly) as double2 (ds_read_b128), 16 fp64 FMA per 4 reads.
// ---------------------------------------------------------------------------
__global__ __launch_bounds__(192) void k1_gram(
    const float* __restrict__ x, double* __restrict__ S,
    double* __restrict__ M)
{
    const int b = blockIdx.x, part = blockIdx.y, tid = threadIdx.x;

    __shared__ double sXT[TTILE * LDT];   // [t][c], 16B-aligned rows
    __shared__ double sMP[192];

    // loader mapping: 3 threads per channel row
    const int lc = tid / 3, lsub = tid - lc * 3;
    const int lt0 = (lsub == 0) ? 0 : (lsub == 1 ? 17 : 34);
    const int lt1 = (lsub == 0) ? 17 : (lsub == 1 ? 34 : 50);
    const bool loader = (lc < CC);

    // Grammian mapping: thread u<136 -> group-pair (gi<=gj) of 16 groups of 4
    int gi = 0, gj = 0;
    if (tid < 136) {
        int g = 0, rem = tid;
        while (rem >= 16 - g) { rem -= (16 - g); ++g; }
        gi = g; gj = g + rem;
    }
    const bool gram = (tid < 136);
    const int c0 = 4 * gi, c1 = 4 * gj;

    double acc[4][4];
#pragma unroll
    for (int a = 0; a < 4; ++a)
#pragma unroll
        for (int c = 0; c < 4; ++c) acc[a][c] = 0.0;
    double macc = 0.0;

    // zero pad channels 62..65
    if (tid < TTILE) {
        sXT[tid * LDT + 62] = 0.0; sXT[tid * LDT + 63] = 0.0;
        sXT[tid * LDT + 64] = 0.0; sXT[tid * LDT + 65] = 0.0;
    }

    const float* xb = x + (size_t)b * CC * TT;
    const int tbase = part * TCHUNK;

    for (int tile = 0; tile < NTILES; ++tile) {
        const int t0 = tbase + tile * TTILE;
        __syncthreads();   // previous tile consumed (also covers pad init)
        if (loader) {
            const float* xr = xb + (size_t)lc * TT + t0;
            for (int t = lt0; t < lt1; ++t) {
                float v = xr[t];
                macc += (double)v;
                sXT[t * LDT + lc] = (double)v;
            }
        }
        __syncthreads();
        if (gram) {
            for (int t = 0; t < TTILE; ++t) {
                const double* rowt = &sXT[t * LDT];
                double2 A0 = *reinterpret_cast<const double2*>(&rowt[c0]);
                double2 A1 = *reinterpret_cast<const double2*>(&rowt[c0 + 2]);
                double2 B0 = *reinterpret_cast<const double2*>(&rowt[c1]);
                double2 B1 = *reinterpret_cast<const double2*>(&rowt[c1 + 2]);
                acc[0][0] += A0.x * B0.x; acc[0][1] += A0.x * B0.y;
                acc[0][2] += A0.x * B1.x; acc[0][3] += A0.x * B1.y;
                acc[1][0] += A0.y * B0.x; acc[1][1] += A0.y * B0.y;
                acc[1][2] += A0.y * B1.x; acc[1][3] += A0.y * B1.y;
                acc[2][0] += A1.x * B0.x; acc[2][1] += A1.x * B0.y;
                acc[2][2] += A1.x * B1.x; acc[2][3] += A1.x * B1.y;
                acc[3][0] += A1.y * B0.x; acc[3][1] += A1.y * B0.y;
                acc[3][2] += A1.y * B1.x; acc[3][3] += A1.y * B1.y;
            }
        }
    }
    __syncthreads();
    sMP[tid] = macc;
    __syncthreads();
    if (tid < CC)
        M[((size_t)b * NPART + part) * 64 + tid] =
            sMP[tid * 3] + sMP[tid * 3 + 1] + sMP[tid * 3 + 2];

    if (gram) {
        double* Sb = S + ((size_t)b * NPART + part) * VECN;
#pragma unroll
        for (int a = 0; a < 4; ++a) {
            int i = c0 + a;
#pragma unroll
            for (int c = 0; c < 4; ++c) {
                int j = c1 + c;
                if (j < CC && i <= j) {
                    int pi = i * CC - (i * (i - 1)) / 2 + (j - i);
                    Sb[pi] = acc[a][c];
                }
            }
        }
    }
}

// ---------------------------------------------------------------------------
// K2: assemble cov_x (packed), A = W cov_x W^T + eps I, ONE-SIDED Jacobi on
//     G = A (fp32 rotation params, fp64 apply, skip-converged pairs, cached
//     norms), then log_cov = G diag(log(lam)/lam^2) G^T -> fp32 triu vec.
// grid = B, block = 512. 1 barrier/round. Lane lt owns rows 4lt..4lt+3
// (contiguous -> ds_read/write_b128).
// ---------------------------------------------------------------------------
__global__ __launch_bounds__(512) void k2_eig(
    const double* __restrict__ S, const double* __restrict__ M,
    const float* __restrict__ cw, float* __restrict__ vecout)
{
    const int b = blockIdx.x, tid = threadIdx.x;

    __shared__ double sG[CC * LDG];    // column-major, rows padded to 64+ w/ 0
    __shared__ double sC[VECN];        // packed upper-tri cov_x
    __shared__ double sU[8 * 64];
    __shared__ double sNorm[64];
    __shared__ double sD[64];
    __shared__ double sMean[64];
    __shared__ int    sPair[61 * NG];
    __shared__ int    sFlag;

    for (int e = tid; e < 61 * NG; e += 512) {
        int r = e / NG, k = e - r * NG;
        int p, q; pairPQ(r, k, p, q);
        sPair[e] = p | (q << 8);
    }
    if (tid < CC) {
        double mm = 0.0;
        for (int p = 0; p < NPART; ++p) mm += M[((size_t)b * NPART + p) * 64 + tid];
        sMean[tid] = mm / (double)TT;
    }
    for (int e = tid; e < CC * LDG; e += 512) sG[e] = 0.0;
    __syncthreads();

    // packed cov_x = (S - T m m^T)/(T-1)
    for (int pi = tid; pi < VECN; pi += 512) {
        int i, j; decodePi(pi, i, j);
        double s = 0.0;
        for (int p = 0; p < NPART; ++p) s += S[((size_t)b * NPART + p) * VECN + pi];
        sC[pi] = (s - (double)TT * sMean[i] * sMean[j]) / 1999.0;
    }
    __syncthreads();

    // A = W C W^T + eps I, chunks of 8 output columns
    const int jj = tid >> 6, kk = tid & 63;
    for (int j0 = 0; j0 < CC; j0 += 8) {
        const int j = j0 + jj;
        if (kk < CC && j < CC) {
            const float* wr = cw + j * CC;
            double a = 0.0; int idx = kk;
            for (int l = 0; l < kk; ++l) { a += sC[idx] * (double)wr[l]; idx += 61 - l; }
            for (int l = kk; l < CC; ++l) { a += sC[idx] * (double)wr[l]; idx += 1; }
            sU[jj * 64 + kk] = a;    // u_j[k] = (C w_j)[k]
        }
        __syncthreads();
        const int i = kk;
        if (i < CC && j < CC && i <= j) {
            const float* wi = cw + i * CC;
            double a = (i == j) ? 1e-3 : 0.0;
            for (int l = 0; l < CC; ++l) a += (double)wi[l] * sU[jj * 64 + l];
            sG[j * LDG + i] = a;
            sG[i * LDG + j] = a;
        }
        __syncthreads();
    }

    // initial column norms n_k = ||g_k||^2
    if (tid < CC) {
        const double* col = &sG[tid * LDG];
        double n = 0.0;
        for (int i2 = 0; i2 < CC; ++i2) n += col[i2] * col[i2];
        sNorm[tid] = n;
    }
    __syncthreads();

    // one-sided Jacobi: group g (16 lanes) handles pair g each round;
    // lane lt owns rows 4lt..4lt+3 (contiguous, b128)
    const int g = tid >> 4, lt = tid & 15;
    const bool act = (g < NG);
    const int r0 = 4 * lt;

    for (int sweep = 0; sweep < 20; ++sweep) {
        if (tid == 0) sFlag = 0;
        __syncthreads();
        for (int r = 0; r < 61; ++r) {
            if (act) {
                int pq = sPair[r * NG + g];
                int p = pq & 255, q = pq >> 8;
                double2* gp = reinterpret_cast<double2*>(&sG[p * LDG + r0]);
                double2* gq = reinterpret_cast<double2*>(&sG[q * LDG + r0]);
                double2 A0 = gp[0], A1 = gp[1];
                double2 B0 = gq[0], B1 = gq[1];
                double d = A0.x * B0.x + A0.y * B0.y + A1.x * B1.x + A1.y * B1.y;
                d += __shfl_xor(d, 8, 16);
                d += __shfl_xor(d, 4, 16);
                d += __shfl_xor(d, 2, 16);
                d += __shfl_xor(d, 1, 16);
                double np = sNorm[p], nq = sNorm[q];
                if (d * d > np * nq * 1e-12) {
                    // fp32 rotation params (residual ~1e-7*|d| < threshold)
                    float thf = (float)(nq - np) / (2.0f * (float)d);
                    float af = fabsf(thf);
                    float tf = 1.0f / (af + sqrtf(af * af + 1.0f));
                    if (thf < 0.0f) tf = -tf;
                    float cf = rsqrtf(tf * tf + 1.0f);
                    double c = (double)cf, sn = (double)(tf * cf);
                    gp[0] = make_double2(c * A0.x - sn * B0.x, c * A0.y - sn * B0.y);
                    gp[1] = make_double2(c * A1.x - sn * B1.x, c * A1.y - sn * B1.y);
                    gq[0] = make_double2(sn * A0.x + c * B0.x, sn * A0.y + c * B0.y);
                    gq[1] = make_double2(sn * A1.x + c * B1.x, sn * A1.y + c * B1.y);
                    if (lt == 0) {
                        double td = (double)tf * d;
                        sNorm[p] = np - td; sNorm[q] = nq + td;
                        sFlag = 1;
                    }
                }
            }
            __syncthreads();
        }
        int flag = sFlag;
        __syncthreads();
        if (!flag) break;
    }

    // lam_k^2 = ||g_k||^2 ; d_k = log(max(lam,1e-6))/lam^2
    if (tid < CC) {
        const double* col = &sG[tid * LDG];
        double n = 0.0;
        for (int i5 = 0; i5 < CC; ++i5) n += col[i5] * col[i5];
        double lamv = sqrt(n);
        sD[tid] = log(fmax(lamv, 1e-6)) / n;
    }
    __syncthreads();

    float* vb = vecout + (size_t)b * VECN;
    for (int pi = tid; pi < VECN; pi += 512) {
        int i, j; decodePi(pi, i, j);
        double a = 0.0;
        for (int k2 = 0; k2 < CC; ++k2)
            a += sD[k2] * sG[k2 * LDG + i] * sG[k2 * LDG + j];
        vb[pi] = (float)a;
    }
}

// ---------------------------------------------------------------------------
// K3: feat = relu(vec @ proj_w^T + proj_b); logits = feat @ head_w^T + head_b
// grid = B, block = 256 (4-way K-split per hidden unit for latency hiding)
// ---------------------------------------------------------------------------
__global__ __launch_bounds__(256) void k3_mlp(
    const float* __restrict__ vecin, const float* __restrict__ pw,
    const float* __restrict__ pb, const float* __restrict__ hw,
    const float* __restrict__ hb, float* __restrict__ out)
{
    const int b = blockIdx.x;
    const int tid = threadIdx.x;
    __shared__ float sv[VECN];
    __shared__ float sp[4][HID];
    __shared__ float sf[HID];
    for (int k = tid; k < VECN; k += 256) sv[k] = vecin[(size_t)b * VECN + k];
    __syncthreads();
    const int h = tid & 63, pp = tid >> 6;
    const int k0 = (pp * VECN) >> 2, k1 = ((pp + 1) * VECN) >> 2;
    float acc = 0.0f;
    const float* w = pw + (size_t)h * VECN;
    for (int k = k0; k < k1; ++k) acc += sv[k] * w[k];
    sp[pp][h] = acc;
    __syncthreads();
    if (tid < HID) {
        float a = sp[0][tid] + sp[1][tid] + sp[2][tid] + sp[3][tid] + pb[tid];
        sf[tid] = fmaxf(a, 0.0f);
    }
    __syncthreads();
    if (tid < NCLS) {
        float o = hb[tid];
        for (int hh = 0; hh < HID; ++hh) o += sf[hh] * hw[tid * HID + hh];
        out[b * NCLS + tid] = o;
    }
}

// ---------------------------------------------------------------------------
extern "C" void kernel_launch(void* const* d_in, const int* in_sizes, int n_in,
                              void* d_out, int out_size, void* d_ws, size_t ws_size,
                              hipStream_t stream)
{
    const float* x  = (const float*)d_in[0];
    const float* cw = (const float*)d_in[1];
    // d_in[2] = conv bias: cancels in covariance, unused
    const float* pw = (const float*)d_in[3];
    const float* pb = (const float*)d_in[4];
    const float* hw = (const float*)d_in[5];
    const float* hb = (const float*)d_in[6];
    float* out = (float*)d_out;

    // workspace: S [B*NPART][VECN] fp64 (16MB), M [B*NPART][64] fp64 (0.5MB),
    //            vec [B][VECN] fp32 (2MB)
    double* S = (double*)d_ws;
    double* M = S + (size_t)BB * NPART * VECN;
    float* vec = (float*)(M + (size_t)BB * NPART * 64);

    dim3 g1(BB, NPART);
    k1_gram<<<g1, 192, 0, stream>>>(x, S, M);
    k2_eig<<<BB, 512, 0, stream>>>(S, M, cw, vec);
    k3_mlp<<<BB, 256, 0, stream>>>(vec, pw, pb, hw, hb, out);
}